// Round 4
// baseline (902.384 us; speedup 1.0000x reference)
//
#include <hip/hip_runtime.h>
#include <hip/hip_cooperative_groups.h>
#include <cstdint>
#include <cstddef>

namespace cg = cooperative_groups;

// Problem constants
#define B_    64
#define H_    8
#define N_    16384
#define M_    64
#define C_    1024
#define IVH_  198          // 3*M+6
#define J_    1584         // H*IVH
#define NSEG_ 16           // segments per batch
#define SEGROWS_ 1024      // rows per segment (NSEG_*SEGROWS_ == N_)

__device__ __forceinline__ float softplus_f(float x) {
    return (x > 20.f) ? x : log1pf(__expf(x));
}
__device__ __forceinline__ float sigmoid_f(float x) {
    return 1.f / (1.f + __expf(-x));
}

// ---------------------------------------------------------------------------
// Kernel 1: iv = x @ W, atomic-free (full K per block). grid (25, 16), block 64.
__global__ __launch_bounds__(64) void k_gemm(const float* __restrict__ x,
                                             const float* __restrict__ W,
                                             float* __restrict__ iv) {
    int lane = threadIdx.x;
    int j = blockIdx.x * 64 + lane;
    bool valid = (j < J_);
    int b0 = blockIdx.y * 4;
    const float* xb = x + (size_t)b0 * C_;
    float a0 = 0.f, a1 = 0.f, a2 = 0.f, a3 = 0.f;
    #pragma unroll 4
    for (int c = 0; c < C_; ++c) {
        float wv = valid ? W[(size_t)c * J_ + j] : 0.f;
        a0 = fmaf(xb[c],           wv, a0);
        a1 = fmaf(xb[C_ + c],      wv, a1);
        a2 = fmaf(xb[2 * C_ + c],  wv, a2);
        a3 = fmaf(xb[3 * C_ + c],  wv, a3);
    }
    if (valid) {
        iv[(size_t)(b0 + 0) * J_ + j] = a0;
        iv[(size_t)(b0 + 1) * J_ + j] = a1;
        iv[(size_t)(b0 + 2) * J_ + j] = a2;
        iv[(size_t)(b0 + 3) * J_ + j] = a3;
    }
}

// ---------------------------------------------------------------------------
// Kernel 2: per-(b,h) parameter extraction. grid 512 blocks, block 64.
__global__ void k_params(const float* __restrict__ iv, const float* __restrict__ bias,
                         float* __restrict__ kbuf, float* __restrict__ P,
                         float* __restrict__ out_e, float* __restrict__ out_a) {
    int bh = blockIdx.x;
    int m  = threadIdx.x;              // 0..63
    int b = bh >> 3, h = bh & 7;
    const float* row = iv + (size_t)b * J_ + h * IVH_;
    const float* bb  = bias + h * IVH_;
    float kv = row[m] + bb[m];
    kbuf[(size_t)bh * 64 + m] = kv;
    float s = kv * kv;
    #pragma unroll
    for (int o = 32; o > 0; o >>= 1) s += __shfl_down(s, o, 64);
    float ev = row[70 + m] + bb[70 + m];            // M+6 = 70
    out_e[(size_t)bh * 64 + m] = sigmoid_f(ev);
    out_a[(size_t)bh * 64 + m] = row[134 + m] + bb[134 + m];  // 2M+6 = 134
    if (m == 0) {
        float knorm = sqrtf(s);
        float v0 = row[64] + bb[64];
        float v1 = row[65] + bb[65];
        float v2 = row[66] + bb[66];
        float v3 = row[67] + bb[67];
        float v4 = row[68] + bb[68];
        float v5 = row[69] + bb[69];
        float beta = softplus_f(v0);
        float g = sigmoid_f(v1);
        float mx = fmaxf(v2, fmaxf(v3, v4));
        float e2 = __expf(v2 - mx), e3 = __expf(v3 - mx), e4 = __expf(v4 - mx);
        float inv = 1.f / (e2 + e3 + e4);
        float gamma = 1.f + softplus_f(v5);
        float* p = P + (size_t)bh * 8;
        p[0] = knorm; p[1] = beta; p[2] = g;
        p[3] = e2 * inv; p[4] = e3 * inv; p[5] = e4 * inv;
        p[6] = gamma;
    }
}

// ---------------------------------------------------------------------------
// Kernel 3: fused cooperative pipeline. 1024 blocks x 256 threads, all
// co-resident (4 blocks/CU: LDS 33.4KB <= 40KB, VGPR capped by launch_bounds).
// Block (b, seg) owns rows [seg*1024, seg*1024+1024).
//  Phase A: z = beta*cos -> LDS (persists across grid syncs); per-block
//           softmax partials -> global; boundary z -> z_bound.
//  sync1 -> final stats; wc->wg in-place over z; ws->wp in-place over wg;
//           sumwp + readAcc atomics.
//  sync2 -> normalized w written straight from LDS; out_rd by seg==0 blocks.
__global__ __launch_bounds__(256, 4) void k_fused(
        const float* __restrict__ mem, const float* __restrict__ kbuf,
        const float* __restrict__ P, const float* __restrict__ wprev,
        float* __restrict__ z_bound, float* __restrict__ pmax,
        float* __restrict__ psum, float* __restrict__ sumwp,
        float* __restrict__ readAcc, float* __restrict__ out_w,
        float* __restrict__ out_rd) {
    __shared__ float z_lds[8 * 1028];   // [h*1028 + row_local], 32.9 KB
    __shared__ float pbuf[64];          // P[b][h][0..7]
    __shared__ float sM[8], sIS[8];
    __shared__ float wg_ext[16];        // [side*8+h] boundary wg
    __shared__ float edge_wg[8];        // prev-chunk row-255 wg
    __shared__ float sums[32];          // sumwp wave partials

    int t = threadIdx.x;
    int blk = blockIdx.x;
    int b = blk >> 4, seg = blk & 15;
    int w = t >> 6, lane = t & 63, sub = lane >> 4, mq = lane & 15;
    int n0 = seg * SEGROWS_;

    // zero sumwp (512) + readAcc (32768): contiguous at sumwp
    if (blk < 130) {
        int idx = blk * 256 + t;
        if (idx < 33280) sumwp[idx] = 0.f;
    }

    // ---- Phase A ----
    float4 kreg[8];
    #pragma unroll
    for (int h = 0; h < 8; ++h)
        kreg[h] = *(const float4*)(kbuf + (((size_t)b * 8 + h) << 6) + mq * 4);
    float beta = 0.f, knorm = 1.f;
    if (mq < 8) {
        const float* p = P + (((size_t)b * 8 + mq) << 3);
        knorm = p[0]; beta = p[1];
    }
    const float* mb = mem + ((size_t)b * N_ + n0) * M_;

    #pragma unroll
    for (int ch = 0; ch < 4; ++ch) {
        #pragma unroll
        for (int rr = 0; rr < 16; ++rr) {
            int rl = ch * 256 + (w << 6) + (rr << 2) + sub;
            float4 mv = *(const float4*)(mb + (size_t)rl * M_ + mq * 4);
            float pr[9];
            #pragma unroll
            for (int h = 0; h < 8; ++h)
                pr[h] = kreg[h].x * mv.x + kreg[h].y * mv.y
                      + kreg[h].z * mv.z + kreg[h].w * mv.w;
            pr[8] = mv.x * mv.x + mv.y * mv.y + mv.z * mv.z + mv.w * mv.w;
            #pragma unroll
            for (int o = 1; o < 16; o <<= 1) {
                #pragma unroll
                for (int i = 0; i < 9; ++i) pr[i] += __shfl_xor(pr[i], o, 64);
            }
            if (mq < 8) {
                float rn = sqrtf(pr[8]);
                z_lds[mq * 1028 + rl] = beta * pr[mq] / (knorm * rn + 1e-16f);
            }
        }
    }
    __syncthreads();

    // boundary z export
    if (t < 16) {
        int side = t >> 3, h = t & 7;
        z_bound[((size_t)(b * 16 + seg) * 2 + side) * 8 + h] =
            z_lds[h * 1028 + (side ? (SEGROWS_ - 1) : 0)];
    }

    // per-block softmax partials: wave w handles h = 2w, 2w+1
    #pragma unroll
    for (int q = 0; q < 2; ++q) {
        int h = w * 2 + q;
        float v[16];
        #pragma unroll
        for (int i = 0; i < 16; ++i) v[i] = z_lds[h * 1028 + lane + i * 64];
        float mx = v[0];
        #pragma unroll
        for (int i = 1; i < 16; ++i) mx = fmaxf(mx, v[i]);
        #pragma unroll
        for (int o = 32; o > 0; o >>= 1) mx = fmaxf(mx, __shfl_down(mx, o, 64));
        mx = __shfl(mx, 0, 64);
        float se = 0.f;
        #pragma unroll
        for (int i = 0; i < 16; ++i) se += __expf(v[i] - mx);
        #pragma unroll
        for (int o = 32; o > 0; o >>= 1) se += __shfl_down(se, o, 64);
        if (lane == 0) {
            pmax[(size_t)(b * 8 + h) * 16 + seg] = mx;
            psum[(size_t)(b * 8 + h) * 16 + seg] = se;
        }
    }

    cg::this_grid().sync();   // ---- sync 1 ----

    // final stats (per block, own b)
    if (t < 8) {
        int h = t;
        const float* pm = pmax + (size_t)(b * 8 + h) * 16;
        const float* ps = psum + (size_t)(b * 8 + h) * 16;
        float mx = pm[0];
        #pragma unroll
        for (int i = 1; i < 16; ++i) mx = fmaxf(mx, pm[i]);
        float s = 0.f;
        #pragma unroll
        for (int i = 0; i < 16; ++i) s += ps[i] * __expf(pm[i] - mx);
        sM[h] = mx; sIS[h] = 1.f / s;
    }
    if (t < 64) pbuf[t] = P[(size_t)b * 64 + t];
    __syncthreads();

    // B0: boundary wg
    if (t < 16) {
        int side = t >> 3, h = t & 7;
        int nbseg = side ? ((seg + 1) & 15) : ((seg + 15) & 15);
        float zb = z_bound[((size_t)(b * 16 + nbseg) * 2 + (side ? 0 : 1)) * 8 + h];
        int nbrow = side ? ((n0 + SEGROWS_) & (N_ - 1)) : ((n0 - 1) & (N_ - 1));
        float g = pbuf[h * 8 + 2];
        float wc = __expf(zb - sM[h]) * sIS[h];
        wg_ext[side * 8 + h] =
            fmaf(g, wc, (1.f - g) * wprev[(((size_t)(b * 8 + h)) << 14) + nbrow]);
    }

    // B1: wc -> wg in place (each thread touches only its own row slots)
    #pragma unroll
    for (int it = 0; it < 4; ++it) {
        int rl = it * 256 + t;
        int n = n0 + rl;
        #pragma unroll
        for (int h = 0; h < 8; ++h) {
            float g = pbuf[h * 8 + 2];
            float wc = __expf(z_lds[h * 1028 + rl] - sM[h]) * sIS[h];
            float wpr = wprev[(((size_t)(b * 8 + h)) << 14) + n];
            z_lds[h * 1028 + rl] = fmaf(g, wc, (1.f - g) * wpr);
        }
    }
    __syncthreads();

    // B2: shift + sharpen, ascending chunks with edge save; wp overwrites wg
    float swp[8];
    #pragma unroll
    for (int h = 0; h < 8; ++h) swp[h] = 0.f;
    for (int it = 0; it < 4; ++it) {
        int rl = it * 256 + t;
        float wmv[8], wpv[8];
        #pragma unroll
        for (int h = 0; h < 8; ++h) {
            float wl;
            if (rl == 0)          wl = wg_ext[h];
            else if (t == 0)      wl = edge_wg[h];
            else                  wl = z_lds[h * 1028 + rl - 1];
            float wr = (rl == SEGROWS_ - 1) ? wg_ext[8 + h]
                                            : z_lds[h * 1028 + rl + 1];
            float wm = z_lds[h * 1028 + rl];
            wmv[h] = wm;
            float s0 = pbuf[h * 8 + 3], s1 = pbuf[h * 8 + 4], s2 = pbuf[h * 8 + 5];
            float gam = pbuf[h * 8 + 6];
            float wsv = s0 * wl + s1 * wm + s2 * wr;
            float v = __powf(wsv, gam);
            wpv[h] = v;
            swp[h] += v;
        }
        __syncthreads();
        if (t == 255) {
            #pragma unroll
            for (int h = 0; h < 8; ++h) edge_wg[h] = wmv[h];
        }
        #pragma unroll
        for (int h = 0; h < 8; ++h) z_lds[h * 1028 + rl] = wpv[h];
        __syncthreads();
    }

    // sumwp: register butterfly -> wave partials -> atomic
    #pragma unroll
    for (int h = 0; h < 8; ++h) {
        float s = swp[h];
        #pragma unroll
        for (int o = 32; o > 0; o >>= 1) s += __shfl_down(s, o, 64);
        if (lane == 0) sums[w * 8 + h] = s;
    }
    __syncthreads();
    if (t < 8)
        atomicAdd(&sumwp[b * 8 + t], sums[t] + sums[8 + t] + sums[16 + t] + sums[24 + t]);

    // B3: weighted read, 16 lanes per row, wp from LDS (broadcast reads)
    float4 acc[8];
    #pragma unroll
    for (int h = 0; h < 8; ++h) acc[h] = make_float4(0.f, 0.f, 0.f, 0.f);
    #pragma unroll
    for (int ch = 0; ch < 4; ++ch) {
        #pragma unroll
        for (int rr = 0; rr < 16; ++rr) {
            int rl = ch * 256 + (w << 6) + (rr << 2) + sub;
            float4 mv = *(const float4*)(mb + (size_t)rl * M_ + mq * 4);
            #pragma unroll
            for (int h = 0; h < 8; ++h) {
                float wv = z_lds[h * 1028 + rl];
                acc[h].x = fmaf(wv, mv.x, acc[h].x);
                acc[h].y = fmaf(wv, mv.y, acc[h].y);
                acc[h].z = fmaf(wv, mv.z, acc[h].z);
                acc[h].w = fmaf(wv, mv.w, acc[h].w);
            }
        }
    }
    #pragma unroll
    for (int h = 0; h < 8; ++h) {
        #pragma unroll
        for (int o = 32; o >= 16; o >>= 1) {
            acc[h].x += __shfl_down(acc[h].x, o, 64);
            acc[h].y += __shfl_down(acc[h].y, o, 64);
            acc[h].z += __shfl_down(acc[h].z, o, 64);
            acc[h].w += __shfl_down(acc[h].w, o, 64);
        }
    }
    if (lane < 16) {
        #pragma unroll
        for (int h = 0; h < 8; ++h) {
            float* dst = readAcc + (size_t)b * 512 + h * 64 + mq * 4;
            atomicAdd(dst + 0, acc[h].x);
            atomicAdd(dst + 1, acc[h].y);
            atomicAdd(dst + 2, acc[h].z);
            atomicAdd(dst + 3, acc[h].w);
        }
    }

    cg::this_grid().sync();   // ---- sync 2 ----

    // normalized w straight from LDS
    float inv[8];
    #pragma unroll
    for (int h = 0; h < 8; ++h) inv[h] = 1.f / (sumwp[b * 8 + h] + 1e-16f);
    #pragma unroll
    for (int it = 0; it < 4; ++it) {
        int rl = it * 256 + t;
        int n = n0 + rl;
        #pragma unroll
        for (int h = 0; h < 8; ++h)
            out_w[(((size_t)(b * 8 + h)) << 14) + n] = z_lds[h * 1028 + rl] * inv[h];
    }
    // read_data by seg==0 blocks
    if (seg == 0) {
        #pragma unroll
        for (int r = 0; r < 2; ++r) {
            int idx = r * 256 + t;
            out_rd[(size_t)b * 512 + idx] =
                readAcc[(size_t)b * 512 + idx] * inv[idx >> 6];
        }
    }
}

// ---------------------------------------------------------------------------
extern "C" void kernel_launch(void* const* d_in, const int* in_sizes, int n_in,
                              void* d_out, int out_size, void* d_ws, size_t ws_size,
                              hipStream_t stream) {
    const float* x     = (const float*)d_in[0];
    const float* mem   = (const float*)d_in[1];
    const float* wprev = (const float*)d_in[2];
    const float* W     = (const float*)d_in[3];
    const float* bias  = (const float*)d_in[4];

    float* out    = (float*)d_out;
    float* out_rd = out;                         // 32768
    float* out_w  = out + 32768;                 // 8388608
    float* out_e  = out + 32768 + 8388608;       // 32768
    float* out_a  = out_e + 32768;               // 32768

    float* ws      = (float*)d_ws;
    float* iv      = ws;                 // 101376
    float* kbuf    = iv + 101376;        // 32768
    float* P       = kbuf + 32768;       // 4096
    float* z_bound = P + 4096;           // 16384
    float* pmax    = z_bound + 16384;    // 8192
    float* psum    = pmax + 8192;        // 8192
    float* sumwp   = psum + 8192;        // 512   (zeroed in-kernel,
    float* readAcc = sumwp + 512;        // 32768  contiguous with sumwp)

    k_gemm  <<<dim3(25, 16), 64, 0, stream>>>(x, W, iv);
    k_params<<<512, 64, 0, stream>>>(iv, bias, kbuf, P, out_e, out_a);

    void* args[] = {
        (void*)&mem, (void*)&kbuf, (void*)&P, (void*)&wprev,
        (void*)&z_bound, (void*)&pmax, (void*)&psum, (void*)&sumwp,
        (void*)&readAcc, (void*)&out_w, (void*)&out_rd
    };
    hipLaunchCooperativeKernel((void*)k_fused, dim3(1024), dim3(256),
                               args, 0, stream);
}